// Round 2
// baseline (340.987 us; speedup 1.0000x reference)
//
#include <hip/hip_runtime.h>

#define NB 8
#define IMH 1024
#define IMW 2048
#define WM 1024          // mask width (fixed by setup_inputs)
#define TH 64
#define TW 32
#define EXTH (TH + 10)   // 74
#define EXTW 44          // TW+10=42, padded to 44 for float4 alignment
#define HSTR 32

__device__ __forceinline__ unsigned int enc_f(float f) {
    unsigned int u = __float_as_uint(f);
    return (u & 0x80000000u) ? ~u : (u | 0x80000000u);
}
__device__ __forceinline__ float dec_f(unsigned int u) {
    u = (u & 0x80000000u) ? (u & 0x7fffffffu) : ~u;
    return __uint_as_float(u);
}

// ws layout (uint index):
//  [0..15]   mn_enc[16]  (img1 b0..7, img2 b0..7)
//  [16..31]  mx_enc[16]
//  float view: wf[32..47] mn, wf[48..63] scale, wf[64..74] g[11]
//  double at uint index 80 (byte 320): global accumulator

__global__ void k_init(unsigned int* ws) {
    int t = threadIdx.x;
    if (t < 16) { ws[t] = 0xFFFFFFFFu; ws[16 + t] = 0u; }
    if (t == 0) *((double*)(ws + 80)) = 0.0;
}

__global__ __launch_bounds__(256) void k_minmax(const float* __restrict__ img1,
                                                const float* __restrict__ img2,
                                                const int* __restrict__ mask_pos,
                                                unsigned int* __restrict__ ws) {
    int bi = blockIdx.x >> 6;        // 0..15
    int img = bi >> 3, b = bi & 7;
    int chunk = blockIdx.x & 63;     // 64 chunks of 16 rows
    const float* base = (img ? img2 : img1)
        + (size_t)b * IMH * IMW + (size_t)(chunk * 16) * IMW + mask_pos[b];
    int tid = threadIdx.x;
    float mn = 3.4e38f, mx = -3.4e38f;
    for (int idx = tid; idx < 16 * WM; idx += 256) {
        int r = idx >> 10, c = idx & (WM - 1);
        float v = base[(size_t)r * IMW + c];
        mn = fminf(mn, v); mx = fmaxf(mx, v);
    }
    for (int off = 32; off; off >>= 1) {
        mn = fminf(mn, __shfl_down(mn, off));
        mx = fmaxf(mx, __shfl_down(mx, off));
    }
    __shared__ float smn[4], smx[4];
    int lane = tid & 63, wid = tid >> 6;
    if (lane == 0) { smn[wid] = mn; smx[wid] = mx; }
    __syncthreads();
    if (tid == 0) {
        mn = fminf(fminf(smn[0], smn[1]), fminf(smn[2], smn[3]));
        mx = fmaxf(fmaxf(smx[0], smx[1]), fmaxf(smx[2], smx[3]));
        atomicMin(&ws[img * 8 + b], enc_f(mn));
        atomicMax(&ws[16 + img * 8 + b], enc_f(mx));
    }
}

__global__ void k_prep(unsigned int* ws) {
    int t = threadIdx.x;
    float* wf = (float*)ws;
    if (t < 16) {
        float mn = dec_f(ws[t]);
        float mx = dec_f(ws[16 + t]);
        float rng = mx - mn;
        float d0 = rng + 1e-8f;
        double D = (double)d0;
        float M = rng / d0;     // running max after each normalization (fp32, matches JAX)
        int b = t & 7;
        for (int j = 0; j < 7 - b; ++j) {   // batch b is normalized 8-b times total
            float dj = M + 1e-8f;
            D *= (double)dj;
            M = M / dj;
        }
        wf[32 + t] = mn;
        wf[48 + t] = (float)(1.0 / D);
    }
    if (t == 0) {
        float gv[11], s = 0.f;
        for (int i = 0; i < 11; ++i) {
            float x = (float)((i - 5) * (i - 5));
            gv[i] = expf(-x / 4.5f);
            s += gv[i];
        }
        for (int i = 0; i < 11; ++i) wf[64 + i] = gv[i] / s;
    }
}

__global__ __launch_bounds__(256) void k_ssim(const float* __restrict__ img1,
                                              const float* __restrict__ img2,
                                              const int* __restrict__ mask_pos,
                                              const unsigned int* __restrict__ ws,
                                              double* __restrict__ acc) {
    __shared__ float t1[EXTH][EXTW];
    __shared__ float t2[EXTH][EXTW];
    __shared__ float hb[5][EXTH][HSTR];
    __shared__ float red[4];

    const float* wf = (const float*)ws;
    int b = blockIdx.z;
    int r0g = blockIdx.y * TH;
    int c0g = blockIdx.x * TW;
    int tid = threadIdx.x;
    int mp = mask_pos[b];
    float mn1 = wf[32 + b],     sc1 = wf[48 + b];
    float mn2 = wf[32 + 8 + b], sc2 = wf[48 + 8 + b];
    float gw[11];
#pragma unroll
    for (int i = 0; i < 11; ++i) gw[i] = wf[64 + i];

    const float* b1 = img1 + (size_t)b * IMH * IMW;
    const float* b2 = img2 + (size_t)b * IMH * IMW;

    // ---- stage normalized tile + halo (zero pad outside the masked slice) ----
    for (int idx = tid; idx < EXTH * EXTW; idx += 256) {
        int r = idx / EXTW, c = idx - r * EXTW;
        int gr = r0g + r - 5, gc = c0g + c - 5;
        float v1 = 0.f, v2 = 0.f;
        if (gr >= 0 && gr < IMH && gc >= 0 && gc < WM) {
            size_t o = (size_t)gr * IMW + (size_t)(mp + gc);
            v1 = (b1[o] - mn1) * sc1;
            v2 = (b2[o] - mn2) * sc2;
        }
        t1[r][c] = v1;
        t2[r][c] = v2;
    }
    __syncthreads();

    // ---- horizontal 11-tap pass: 5 channels (m1, m2, m1^2, m2^2, m1*m2) ----
    for (int task = tid; task < EXTH * 8; task += 256) {
        int row = task >> 3, cg = task & 7;
        int c0 = cg * 4;
        float A[16], Bv[16];
#pragma unroll
        for (int q = 0; q < 4; ++q) {
            float4 ta = *(const float4*)&t1[row][c0 + 4 * q];
            float4 tb = *(const float4*)&t2[row][c0 + 4 * q];
            A[4*q+0] = ta.x; A[4*q+1] = ta.y; A[4*q+2] = ta.z; A[4*q+3] = ta.w;
            Bv[4*q+0] = tb.x; Bv[4*q+1] = tb.y; Bv[4*q+2] = tb.z; Bv[4*q+3] = tb.w;
        }
        float s[5][4];
#pragma unroll
        for (int ch = 0; ch < 5; ++ch)
#pragma unroll
            for (int oc = 0; oc < 4; ++oc) s[ch][oc] = 0.f;
#pragma unroll
        for (int e = 0; e < 16; ++e) {
            float a = A[e], bb = Bv[e];
            float paa = a * a, pbb = bb * bb, pab = a * bb;
#pragma unroll
            for (int oc = 0; oc < 4; ++oc) {
                int k = e - oc;
                if (k >= 0 && k < 11) {
                    float w = gw[k];
                    s[0][oc] = fmaf(w, a,   s[0][oc]);
                    s[1][oc] = fmaf(w, bb,  s[1][oc]);
                    s[2][oc] = fmaf(w, paa, s[2][oc]);
                    s[3][oc] = fmaf(w, pbb, s[3][oc]);
                    s[4][oc] = fmaf(w, pab, s[4][oc]);
                }
            }
        }
#pragma unroll
        for (int ch = 0; ch < 5; ++ch) {
            float4 o;
            o.x = s[ch][0]; o.y = s[ch][1]; o.z = s[ch][2]; o.w = s[ch][3];
            *(float4*)&hb[ch][row][c0] = o;
        }
    }
    __syncthreads();

    // ---- vertical 11-tap pass + SSIM, 4x4 outputs per thread (128 threads) ----
    float local = 0.f;
    if (tid < 128) {
        int rq = tid >> 3, cg = tid & 7;
        int r0 = rq * 4, c0 = cg * 4;
        float a[5][4][4];
#pragma unroll
        for (int ch = 0; ch < 5; ++ch)
#pragma unroll
            for (int ro = 0; ro < 4; ++ro)
#pragma unroll
                for (int cc = 0; cc < 4; ++cc) a[ch][ro][cc] = 0.f;
#pragma unroll
        for (int jr = 0; jr < 14; ++jr) {   // rows r0 .. r0+13 (max 73, in bounds)
            float v[5][4];
#pragma unroll
            for (int ch = 0; ch < 5; ++ch) {
                float4 tv = *(const float4*)&hb[ch][r0 + jr][c0];
                v[ch][0] = tv.x; v[ch][1] = tv.y; v[ch][2] = tv.z; v[ch][3] = tv.w;
            }
#pragma unroll
            for (int ro = 0; ro < 4; ++ro) {
                int k = jr - ro;
                if (k >= 0 && k < 11) {
                    float w = gw[k];
#pragma unroll
                    for (int ch = 0; ch < 5; ++ch)
#pragma unroll
                        for (int cc = 0; cc < 4; ++cc)
                            a[ch][ro][cc] = fmaf(w, v[ch][cc], a[ch][ro][cc]);
                }
            }
        }
#pragma unroll
        for (int ro = 0; ro < 4; ++ro) {
#pragma unroll
            for (int cc = 0; cc < 4; ++cc) {
                float mu1 = a[0][ro][cc], mu2 = a[1][ro][cc];
                float e11 = a[2][ro][cc], e22 = a[3][ro][cc], e12 = a[4][ro][cc];
                float m11 = mu1 * mu1, m22 = mu2 * mu2, m12 = mu1 * mu2;
                float s1v = e11 - m11, s2v = e22 - m22, s12 = e12 - m12;
                float num = (2.f * m12 + 1e-4f) * (2.f * s12 + 9e-4f);
                float den = (m11 + m22 + 1e-4f) * (s1v + s2v + 9e-4f);
                local += num / den;
            }
        }
    }
    for (int off = 32; off; off >>= 1) local += __shfl_down(local, off);
    int lane = tid & 63, wid = tid >> 6;
    if (lane == 0) red[wid] = local;
    __syncthreads();
    if (tid == 0) {
        double s = (double)red[0] + (double)red[1] + (double)red[2] + (double)red[3];
        atomicAdd(acc, s);
    }
}

__global__ void k_final(const double* __restrict__ acc, float* __restrict__ out) {
    out[0] = (float)(acc[0] * (1.0 / 8388608.0));   // mean over 8*1*1024*1024
}

extern "C" void kernel_launch(void* const* d_in, const int* in_sizes, int n_in,
                              void* d_out, int out_size, void* d_ws, size_t ws_size,
                              hipStream_t stream) {
    const float* img1 = (const float*)d_in[0];
    const float* img2 = (const float*)d_in[1];
    const int* mask_pos = (const int*)d_in[2];
    unsigned int* ws = (unsigned int*)d_ws;
    double* acc = (double*)(ws + 80);
    float* out = (float*)d_out;

    hipLaunchKernelGGL(k_init, dim3(1), dim3(64), 0, stream, ws);
    hipLaunchKernelGGL(k_minmax, dim3(1024), dim3(256), 0, stream, img1, img2, mask_pos, ws);
    hipLaunchKernelGGL(k_prep, dim3(1), dim3(64), 0, stream, ws);
    hipLaunchKernelGGL(k_ssim, dim3(WM / TW, IMH / TH, NB), dim3(256), 0, stream,
                       img1, img2, mask_pos, ws, acc);
    hipLaunchKernelGGL(k_final, dim3(1), dim3(1), 0, stream, acc, out);
}

// Round 3
// 231.482 us; speedup vs baseline: 1.4731x; 1.4731x over previous
//
#include <hip/hip_runtime.h>

#define NB 8
#define IMH 1024
#define IMW 2048
#define WM 1024          // mask width (fixed by setup_inputs)
#define RPB 32           // output rows per block
#define CPB 256          // output cols per block (1 col per thread)
#define RBW 272          // row buffer entries: mask cols cb-8 .. cb+263

__device__ __forceinline__ unsigned int enc_f(float f) {
    unsigned int u = __float_as_uint(f);
    return (u & 0x80000000u) ? ~u : (u | 0x80000000u);
}
__device__ __forceinline__ float dec_f(unsigned int u) {
    u = (u & 0x80000000u) ? (u & 0x7fffffffu) : ~u;
    return __uint_as_float(u);
}

// ws layout (uint index):
//  [0..15]  mn_enc (img1 b0..7, img2 b0..7), [16..31] mx_enc
//  double at uint index 80 (byte 320): global accumulator

__global__ void k_init(unsigned int* ws) {
    int t = threadIdx.x;
    if (t < 16) { ws[t] = 0xFFFFFFFFu; ws[16 + t] = 0u; }
    if (t == 0) *((double*)(ws + 80)) = 0.0;
}

__global__ __launch_bounds__(256) void k_minmax(const float* __restrict__ img1,
                                                const float* __restrict__ img2,
                                                const int* __restrict__ mask_pos,
                                                unsigned int* __restrict__ ws) {
    int bi = blockIdx.x >> 6;        // 0..15
    int img = bi >> 3, b = bi & 7;
    int chunk = blockIdx.x & 63;     // 64 chunks of 16 rows
    const float* base = (img ? img2 : img1)
        + (size_t)b * IMH * IMW + (size_t)(chunk * 16) * IMW + mask_pos[b];
    int tid = threadIdx.x;
    float mn = 3.4e38f, mx = -3.4e38f;
    for (int idx = tid; idx < 16 * WM; idx += 256) {
        int r = idx >> 10, c = idx & (WM - 1);
        float v = base[(size_t)r * IMW + c];
        mn = fminf(mn, v); mx = fmaxf(mx, v);
    }
    for (int off = 32; off; off >>= 1) {
        mn = fminf(mn, __shfl_down(mn, off));
        mx = fmaxf(mx, __shfl_down(mx, off));
    }
    __shared__ float smn[4], smx[4];
    int lane = tid & 63, wid = tid >> 6;
    if (lane == 0) { smn[wid] = mn; smx[wid] = mx; }
    __syncthreads();
    if (tid == 0) {
        mn = fminf(fminf(smn[0], smn[1]), fminf(smn[2], smn[3]));
        mx = fmaxf(fmaxf(smx[0], smx[1]), fmaxf(smx[2], smx[3]));
        atomicMin(&ws[img * 8 + b], enc_f(mn));
        atomicMax(&ws[16 + img * 8 + b], enc_f(mx));
    }
}

// Fused sliding-row SSIM: horizontal 11-tap gather from an LDS row buffer,
// vertical 11-tap register scatter (acc[11][5], statically indexed by the
// 11-unrolled phase loop), one barrier per input row.
__global__ __launch_bounds__(256) void k_ssim(const float* __restrict__ img1,
                                              const float* __restrict__ img2,
                                              const int* __restrict__ mask_pos,
                                              const unsigned int* __restrict__ ws,
                                              double* __restrict__ acc_g) {
    __shared__ float rb[2][2][RBW];
    __shared__ float red[4];

    const int tid = threadIdx.x;
    const int b  = blockIdx.z;
    const int cb = blockIdx.x * CPB;
    const int r0 = blockIdx.y * RPB;
    const int mp = mask_pos[b];

    // normalization params (per-thread redundant, identical math to prior k_prep)
    float mn1, sc1, mn2, sc2;
    {
        float mnA = dec_f(ws[b]),     mxA = dec_f(ws[16 + b]);
        float mnB = dec_f(ws[8 + b]), mxB = dec_f(ws[24 + b]);
        float rngA = mxA - mnA; float d0A = rngA + 1e-8f; double DA = (double)d0A; float MA = rngA / d0A;
        float rngB = mxB - mnB; float d0B = rngB + 1e-8f; double DB = (double)d0B; float MB = rngB / d0B;
        for (int j = 0; j < 7 - b; ++j) {
            float djA = MA + 1e-8f; DA *= (double)djA; MA = MA / djA;
            float djB = MB + 1e-8f; DB *= (double)djB; MB = MB / djB;
        }
        mn1 = mnA; sc1 = (float)(1.0 / DA);
        mn2 = mnB; sc2 = (float)(1.0 / DB);
    }
    float gw[11];
    {
        float s = 0.f;
#pragma unroll
        for (int k = 0; k < 11; ++k) {
            float x = (float)((k - 5) * (k - 5));
            gw[k] = expf(-x / 4.5f);
            s += gw[k];
        }
#pragma unroll
        for (int k = 0; k < 11; ++k) gw[k] = gw[k] / s;
    }

    const float* b1 = img1 + (size_t)b * (IMH * IMW);
    const float* b2 = img2 + (size_t)b * (IMH * IMW);

    float acc[11][5];
#pragma unroll
    for (int s = 0; s < 11; ++s)
#pragma unroll
        for (int ch = 0; ch < 5; ++ch) acc[s][ch] = 0.f;

    float local = 0.f;

    // prologue: stage input row r0-5 into parity 0
    {
        int rn = r0 - 5;
        float va = 0.f, vb = 0.f, wa = 0.f, wb = 0.f;
        if ((unsigned)rn < (unsigned)IMH) {
            int mcA = cb + tid - 8;
            if ((unsigned)mcA < (unsigned)WM) {
                size_t o = (size_t)rn * IMW + (size_t)(mp + mcA);
                va = (b1[o] - mn1) * sc1; vb = (b2[o] - mn2) * sc2;
            }
            if (tid < RBW - 256) {
                int mcB = cb + 248 + tid;
                if ((unsigned)mcB < (unsigned)WM) {
                    size_t o = (size_t)rn * IMW + (size_t)(mp + mcB);
                    wa = (b1[o] - mn1) * sc1; wb = (b2[o] - mn2) * sc2;
                }
            }
        }
        rb[0][0][tid] = va; rb[0][1][tid] = vb;
        if (tid < RBW - 256) { rb[0][0][256 + tid] = wa; rb[0][1][256 + tid] = wb; }
        __syncthreads();
    }

#pragma unroll 1
    for (int g = 0; g < 4; ++g) {
#pragma unroll
        for (int p = 0; p < 11; ++p) {
            const int i = g * 11 + p;       // iteration 0..43, input row r0-5+i
            const int par = (g + p) & 1;

            // issue prefetch of next input row (hidden under compute)
            int rn = r0 - 4 + i;
            float va = 0.f, vb = 0.f, wa = 0.f, wb = 0.f;
            if ((unsigned)rn < (unsigned)IMH) {
                int mcA = cb + tid - 8;
                if ((unsigned)mcA < (unsigned)WM) {
                    size_t o = (size_t)rn * IMW + (size_t)(mp + mcA);
                    va = (b1[o] - mn1) * sc1; vb = (b2[o] - mn2) * sc2;
                }
                if (tid < RBW - 256) {
                    int mcB = cb + 248 + tid;
                    if ((unsigned)mcB < (unsigned)WM) {
                        size_t o = (size_t)rn * IMW + (size_t)(mp + mcB);
                        wa = (b1[o] - mn1) * sc1; wb = (b2[o] - mn2) * sc2;
                    }
                }
            }

            // horizontal 11-tap, 5 channels, from LDS (consecutive-lane reads)
            const float* c0p = &rb[par][0][tid + 3];
            const float* c1p = &rb[par][1][tid + 3];
            float ha = 0.f, hb = 0.f, haa = 0.f, hbb = 0.f, hab = 0.f;
#pragma unroll
            for (int k = 0; k < 11; ++k) {
                float av = c0p[k], bv = c1p[k], w = gw[k];
                ha  = fmaf(w, av, ha);
                hb  = fmaf(w, bv, hb);
                haa = fmaf(w, av * av, haa);
                hbb = fmaf(w, bv * bv, hbb);
                hab = fmaf(w, av * bv, hab);
            }

            // vertical scatter into 11 pending output rows (static indices)
#pragma unroll
            for (int s = 0; s < 11; ++s) {
                const float w = gw[(p + 10 - s) % 11];
                acc[s][0] = fmaf(w, ha,  acc[s][0]);
                acc[s][1] = fmaf(w, hb,  acc[s][1]);
                acc[s][2] = fmaf(w, haa, acc[s][2]);
                acc[s][3] = fmaf(w, hbb, acc[s][3]);
                acc[s][4] = fmaf(w, hab, acc[s][4]);
            }

            // slot p completes output row r0 + i - 10
            if (i >= 10 && i <= 41) {
                float mu1 = acc[p][0], mu2 = acc[p][1];
                float e11 = acc[p][2], e22 = acc[p][3], e12 = acc[p][4];
                float m11 = mu1 * mu1, m22 = mu2 * mu2, m12 = mu1 * mu2;
                float num = (2.f * m12 + 1e-4f) * (2.f * (e12 - m12) + 9e-4f);
                float den = (m11 + m22 + 1e-4f) * ((e11 - m11) + (e22 - m22) + 9e-4f);
                local += num / den;
            }
            acc[p][0] = 0.f; acc[p][1] = 0.f; acc[p][2] = 0.f;
            acc[p][3] = 0.f; acc[p][4] = 0.f;

            // commit prefetched row to the other buffer; single barrier per row
            rb[par ^ 1][0][tid] = va; rb[par ^ 1][1][tid] = vb;
            if (tid < RBW - 256) { rb[par ^ 1][0][256 + tid] = wa; rb[par ^ 1][1][256 + tid] = wb; }
            __syncthreads();
        }
    }

    for (int off = 32; off; off >>= 1) local += __shfl_down(local, off);
    int lane = tid & 63, wid = tid >> 6;
    if (lane == 0) red[wid] = local;
    __syncthreads();
    if (tid == 0) {
        double s = (double)red[0] + (double)red[1] + (double)red[2] + (double)red[3];
        atomicAdd(acc_g, s);
    }
}

__global__ void k_final(const double* __restrict__ acc, float* __restrict__ out) {
    out[0] = (float)(acc[0] * (1.0 / 8388608.0));   // mean over 8*1*1024*1024
}

extern "C" void kernel_launch(void* const* d_in, const int* in_sizes, int n_in,
                              void* d_out, int out_size, void* d_ws, size_t ws_size,
                              hipStream_t stream) {
    const float* img1 = (const float*)d_in[0];
    const float* img2 = (const float*)d_in[1];
    const int* mask_pos = (const int*)d_in[2];
    unsigned int* ws = (unsigned int*)d_ws;
    double* acc = (double*)(ws + 80);
    float* out = (float*)d_out;

    hipLaunchKernelGGL(k_init, dim3(1), dim3(64), 0, stream, ws);
    hipLaunchKernelGGL(k_minmax, dim3(1024), dim3(256), 0, stream, img1, img2, mask_pos, ws);
    hipLaunchKernelGGL(k_ssim, dim3(WM / CPB, IMH / RPB, NB), dim3(256), 0, stream,
                       img1, img2, mask_pos, ws, acc);
    hipLaunchKernelGGL(k_final, dim3(1), dim3(1), 0, stream, acc, out);
}

// Round 4
// 218.230 us; speedup vs baseline: 1.5625x; 1.0607x over previous
//
#include <hip/hip_runtime.h>

#define NB 8
#define IMH 1024
#define IMW 2048
#define WM 1024          // mask width (fixed by setup_inputs)
#define RPB 32           // output rows per block
#define CPB 256          // output cols per block (1 col per thread)

__device__ __forceinline__ unsigned int enc_f(float f) {
    unsigned int u = __float_as_uint(f);
    return (u & 0x80000000u) ? ~u : (u | 0x80000000u);
}
__device__ __forceinline__ float dec_f(unsigned int u) {
    u = (u & 0x80000000u) ? (u & 0x7fffffffu) : ~u;
    return __uint_as_float(u);
}

// ws layout (uint index):
//  [0..15]  mn_enc (img1 b0..7, img2 b0..7), [16..31] mx_enc
//  double at uint index 80 (byte 320): global accumulator

__global__ void k_init(unsigned int* ws) {
    int t = threadIdx.x;
    if (t < 16) { ws[t] = 0xFFFFFFFFu; ws[16 + t] = 0u; }
    if (t == 0) *((double*)(ws + 80)) = 0.0;
}

__global__ __launch_bounds__(256) void k_minmax(const float* __restrict__ img1,
                                                const float* __restrict__ img2,
                                                const int* __restrict__ mask_pos,
                                                unsigned int* __restrict__ ws) {
    int bi = blockIdx.x >> 7;        // 0..15 (img,b)
    int img = bi >> 3, b = bi & 7;
    int rg = blockIdx.x & 127;       // 128 groups of 8 rows
    const float* base = (img ? img2 : img1)
        + (size_t)b * (IMH * IMW) + (size_t)(rg * 8) * IMW + mask_pos[b];
    int tid = threadIdx.x;
    float mn = 3.4e38f, mx = -3.4e38f;
    for (int r = 0; r < 8; ++r) {
        const float* p = base + (size_t)r * IMW;
        unsigned mis = ((unsigned)(uintptr_t)p >> 2) & 3u;  // dword misalign vs 16B
        unsigned s = (4u - mis) & 3u;                       // first aligned dword
        int nf4 = (int)((1024u - s) >> 2);
        if (tid < nf4) {
            float4 v = *(const float4*)(p + s + 4 * tid);
            mn = fminf(mn, fminf(fminf(v.x, v.y), fminf(v.z, v.w)));
            mx = fmaxf(mx, fmaxf(fmaxf(v.x, v.y), fmaxf(v.z, v.w)));
        }
        if (tid >= 248) {            // head (s dwords) + tail (<=3 dwords)
            unsigned e = tid - 248;  // 0..7
            unsigned rem0 = s + 4u * (unsigned)nf4;
            unsigned tc = 1024u - rem0;
            unsigned idx = 0; bool ok = false;
            if (e < s) { idx = e; ok = true; }
            else if (e >= 4u && (e - 4u) < tc) { idx = rem0 + (e - 4u); ok = true; }
            if (ok) { float v = p[idx]; mn = fminf(mn, v); mx = fmaxf(mx, v); }
        }
    }
    for (int off = 32; off; off >>= 1) {
        mn = fminf(mn, __shfl_down(mn, off));
        mx = fmaxf(mx, __shfl_down(mx, off));
    }
    __shared__ float smn[4], smx[4];
    int lane = tid & 63, wid = tid >> 6;
    if (lane == 0) { smn[wid] = mn; smx[wid] = mx; }
    __syncthreads();
    if (tid == 0) {
        mn = fminf(fminf(smn[0], smn[1]), fminf(smn[2], smn[3]));
        mx = fmaxf(fmaxf(smx[0], smx[1]), fmaxf(smx[2], smx[3]));
        atomicMin(&ws[img * 8 + b], enc_f(mn));
        atomicMax(&ws[16 + img * 8 + b], enc_f(mx));
    }
}

// Fused sliding-row SSIM. Hoisted column predicates, running uint row offset,
// interleaved (a,b) LDS pairs read as ds_read_b64, overwrite-mul on each
// accumulator slot's first tap (bit-identical to fma-into-zero).
__global__ __launch_bounds__(256) void k_ssim(const float* __restrict__ img1,
                                              const float* __restrict__ img2,
                                              const int* __restrict__ mask_pos,
                                              const unsigned int* __restrict__ ws,
                                              double* __restrict__ acc_g) {
    __shared__ float rb[2][1024];    // 512 interleaved (a,b) pairs per buffer
    __shared__ float red[4];

    const int tid = threadIdx.x;
    const int b  = blockIdx.z;
    const int cb = blockIdx.x * CPB;
    const int r0 = blockIdx.y * RPB;
    const int mp = mask_pos[b];

    // normalization params (identical math to the bit-exact round-3 version)
    float mn1, sc1, mn2, sc2;
    {
        float mnA = dec_f(ws[b]),     mxA = dec_f(ws[16 + b]);
        float mnB = dec_f(ws[8 + b]), mxB = dec_f(ws[24 + b]);
        float rngA = mxA - mnA; float d0A = rngA + 1e-8f; double DA = (double)d0A; float MA = rngA / d0A;
        float rngB = mxB - mnB; float d0B = rngB + 1e-8f; double DB = (double)d0B; float MB = rngB / d0B;
        for (int j = 0; j < 7 - b; ++j) {
            float djA = MA + 1e-8f; DA *= (double)djA; MA = MA / djA;
            float djB = MB + 1e-8f; DB *= (double)djB; MB = MB / djB;
        }
        mn1 = mnA; sc1 = (float)(1.0 / DA);
        mn2 = mnB; sc2 = (float)(1.0 / DB);
    }
    float gw[11];
    {
        float s = 0.f;
#pragma unroll
        for (int k = 0; k < 11; ++k) {
            float x = (float)((k - 5) * (k - 5));
            gw[k] = expf(-x / 4.5f);
            s += gw[k];
        }
#pragma unroll
        for (int k = 0; k < 11; ++k) gw[k] = gw[k] / s;
    }

    // scalar bases pre-offset to row r0-5 (never dereferenced when row invalid)
    const float* bs1 = img1 + (size_t)b * (IMH * IMW) + (ptrdiff_t)(r0 - 5) * IMW + mp;
    const float* bs2 = img2 + (size_t)b * (IMH * IMW) + (ptrdiff_t)(r0 - 5) * IMW + mp;

    // column predicates / clamped offsets — invariant across rows
    const int mcA = cb + tid - 8;                      // buffer entry tid
    const bool okA = (unsigned)mcA < (unsigned)WM;
    const int mcB = cb + 248 + tid;                    // buffer entry 256+tid
    const bool okB = (tid < 16) && ((unsigned)mcB < (unsigned)WM);
    unsigned voffA = (unsigned)(okA ? mcA : 0);
    unsigned voffB = (unsigned)(((unsigned)mcB < (unsigned)WM) ? mcB : 0);

    float acc[11][5];
#pragma unroll
    for (int s = 0; s < 11; ++s)
#pragma unroll
        for (int ch = 0; ch < 5; ++ch) acc[s][ch] = 0.f;
    float local = 0.f;

    const float* cur = &rb[0][0];
    float* nxt;

    // prologue: stage row r0-5 into buffer 0
    {
        float va = 0.f, vb = 0.f, wa = 0.f, wb = 0.f;
        if ((unsigned)(r0 - 5) < (unsigned)IMH) {
            float x1 = bs1[voffA], x2 = bs2[voffA];
            float y1 = bs1[voffB], y2 = bs2[voffB];
            va = okA ? (x1 - mn1) * sc1 : 0.f;
            vb = okA ? (x2 - mn2) * sc2 : 0.f;
            wa = okB ? (y1 - mn1) * sc1 : 0.f;
            wb = okB ? (y2 - mn2) * sc2 : 0.f;
        }
        voffA += IMW; voffB += IMW;
        float* w0 = (float*)&rb[0][0];
        *(float2*)&w0[2 * tid] = make_float2(va, vb);
        *(float2*)&w0[2 * (256 + tid)] = make_float2(wa, wb);
        __syncthreads();
    }
    nxt = (float*)&rb[1][0];

#pragma unroll 1
    for (int g = 0; g < 4; ++g) {
#pragma unroll
        for (int p = 0; p < 11; ++p) {
            const int i = g * 11 + p;          // consumes input row r0-5+i

            // prefetch next input row (r0-4+i); row guard is block-uniform
            float va = 0.f, vb = 0.f, wa = 0.f, wb = 0.f;
            if ((unsigned)(r0 - 4 + i) < (unsigned)IMH) {
                float x1 = bs1[voffA], x2 = bs2[voffA];
                float y1 = bs1[voffB], y2 = bs2[voffB];
                va = okA ? (x1 - mn1) * sc1 : 0.f;
                vb = okA ? (x2 - mn2) * sc2 : 0.f;
                wa = okB ? (y1 - mn1) * sc1 : 0.f;
                wb = okB ? (y2 - mn2) * sc2 : 0.f;
            }
            voffA += IMW; voffB += IMW;

            // horizontal 11-tap, 5 channels, paired ds_read_b64
            float ha = 0.f, hbv = 0.f, haa = 0.f, hbb = 0.f, hab = 0.f;
#pragma unroll
            for (int k = 0; k < 11; ++k) {
                float2 e = *(const float2*)&cur[2 * (tid + 3 + k)];
                float av = e.x, bv = e.y, w = gw[k];
                ha  = fmaf(w, av, ha);
                hbv = fmaf(w, bv, hbv);
                haa = fmaf(w, av * av, haa);
                hbb = fmaf(w, bv * bv, hbb);
                hab = fmaf(w, av * bv, hab);
            }

            // vertical scatter; slot (p+10)%11 starts its window: overwrite-mul
#pragma unroll
            for (int s = 0; s < 11; ++s) {
                const float w = gw[(p + 10 - s) % 11];
                if (s == (p + 10) % 11) {
                    acc[s][0] = w * ha;  acc[s][1] = w * hbv; acc[s][2] = w * haa;
                    acc[s][3] = w * hbb; acc[s][4] = w * hab;
                } else {
                    acc[s][0] = fmaf(w, ha,  acc[s][0]);
                    acc[s][1] = fmaf(w, hbv, acc[s][1]);
                    acc[s][2] = fmaf(w, haa, acc[s][2]);
                    acc[s][3] = fmaf(w, hbb, acc[s][3]);
                    acc[s][4] = fmaf(w, hab, acc[s][4]);
                }
            }

            // slot p completes output row r0 + i - 10
            if (i >= 10 && i <= 41) {
                float mu1 = acc[p][0], mu2 = acc[p][1];
                float e11 = acc[p][2], e22 = acc[p][3], e12 = acc[p][4];
                float m11 = mu1 * mu1, m22 = mu2 * mu2, m12 = mu1 * mu2;
                float num = (2.f * m12 + 1e-4f) * (2.f * (e12 - m12) + 9e-4f);
                float den = (m11 + m22 + 1e-4f) * ((e11 - m11) + (e22 - m22) + 9e-4f);
                local += __fdividef(num, den);
            }

            // commit prefetched row; one barrier per row; swap buffers
            *(float2*)&nxt[2 * tid] = make_float2(va, vb);
            *(float2*)&nxt[2 * (256 + tid)] = make_float2(wa, wb);
            __syncthreads();
            { const float* t = cur; cur = nxt; nxt = (float*)t; }
        }
    }

    for (int off = 32; off; off >>= 1) local += __shfl_down(local, off);
    int lane = tid & 63, wid = tid >> 6;
    if (lane == 0) red[wid] = local;
    __syncthreads();
    if (tid == 0) {
        double s = (double)red[0] + (double)red[1] + (double)red[2] + (double)red[3];
        atomicAdd(acc_g, s);
    }
}

__global__ void k_final(const double* __restrict__ acc, float* __restrict__ out) {
    out[0] = (float)(acc[0] * (1.0 / 8388608.0));   // mean over 8*1*1024*1024
}

extern "C" void kernel_launch(void* const* d_in, const int* in_sizes, int n_in,
                              void* d_out, int out_size, void* d_ws, size_t ws_size,
                              hipStream_t stream) {
    const float* img1 = (const float*)d_in[0];
    const float* img2 = (const float*)d_in[1];
    const int* mask_pos = (const int*)d_in[2];
    unsigned int* ws = (unsigned int*)d_ws;
    double* acc = (double*)(ws + 80);
    float* out = (float*)d_out;

    hipLaunchKernelGGL(k_init, dim3(1), dim3(64), 0, stream, ws);
    hipLaunchKernelGGL(k_minmax, dim3(2048), dim3(256), 0, stream, img1, img2, mask_pos, ws);
    hipLaunchKernelGGL(k_ssim, dim3(WM / CPB, IMH / RPB, NB), dim3(256), 0, stream,
                       img1, img2, mask_pos, ws, acc);
    hipLaunchKernelGGL(k_final, dim3(1), dim3(1), 0, stream, acc, out);
}

// Round 7
// 210.216 us; speedup vs baseline: 1.6221x; 1.0381x over previous
//
#include <hip/hip_runtime.h>

#define NB 8
#define IMH 1024
#define IMW 2048
#define WM 1024          // mask width (fixed by setup_inputs)
#define RPB 32           // output rows per block
#define CPB 256          // output cols per block (1 col per thread)

// Raw barrier: LDS visibility needs lgkmcnt(0) only; global prefetch loads
// stay in flight (no vmcnt drain — the whole point vs __syncthreads()).
#define ROW_BARRIER() do { \
    asm volatile("s_waitcnt lgkmcnt(0)" ::: "memory"); \
    __builtin_amdgcn_s_barrier(); \
} while (0)

__device__ __forceinline__ unsigned int enc_f(float f) {
    unsigned int u = __float_as_uint(f);
    return (u & 0x80000000u) ? ~u : (u | 0x80000000u);
}
__device__ __forceinline__ float dec_f(unsigned int u) {
    u = (u & 0x80000000u) ? (u & 0x7fffffffu) : ~u;
    return __uint_as_float(u);
}

// ws layout (uint index):
//  [0..15]  mn_enc (img1 b0..7, img2 b0..7), [16..31] mx_enc
//  double at uint index 80 (byte 320): global accumulator

__global__ void k_init(unsigned int* ws) {
    int t = threadIdx.x;
    if (t < 16) { ws[t] = 0xFFFFFFFFu; ws[16 + t] = 0u; }
    if (t == 0) *((double*)(ws + 80)) = 0.0;
}

__global__ __launch_bounds__(256) void k_minmax(const float* __restrict__ img1,
                                                const float* __restrict__ img2,
                                                const int* __restrict__ mask_pos,
                                                unsigned int* __restrict__ ws) {
    int bi = blockIdx.x >> 7;        // 0..15 (img,b)
    int img = bi >> 3, b = bi & 7;
    int rg = blockIdx.x & 127;       // 128 groups of 8 rows
    const float* base = (img ? img2 : img1)
        + (size_t)b * (IMH * IMW) + (size_t)(rg * 8) * IMW + mask_pos[b];
    int tid = threadIdx.x;
    float mn = 3.4e38f, mx = -3.4e38f;
    for (int r = 0; r < 8; ++r) {
        const float* p = base + (size_t)r * IMW;
        unsigned mis = ((unsigned)(uintptr_t)p >> 2) & 3u;  // dword misalign vs 16B
        unsigned s = (4u - mis) & 3u;                       // first aligned dword
        int nf4 = (int)((1024u - s) >> 2);
        if (tid < nf4) {
            float4 v = *(const float4*)(p + s + 4 * tid);
            mn = fminf(mn, fminf(fminf(v.x, v.y), fminf(v.z, v.w)));
            mx = fmaxf(mx, fmaxf(fmaxf(v.x, v.y), fmaxf(v.z, v.w)));
        }
        if (tid >= 248) {            // head (s dwords) + tail (<=3 dwords)
            unsigned e = tid - 248;  // 0..7
            unsigned rem0 = s + 4u * (unsigned)nf4;
            unsigned tc = 1024u - rem0;
            unsigned idx = 0; bool ok = false;
            if (e < s) { idx = e; ok = true; }
            else if (e >= 4u && (e - 4u) < tc) { idx = rem0 + (e - 4u); ok = true; }
            if (ok) { float v = p[idx]; mn = fminf(mn, v); mx = fmaxf(mx, v); }
        }
    }
    for (int off = 32; off; off >>= 1) {
        mn = fminf(mn, __shfl_down(mn, off));
        mx = fmaxf(mx, __shfl_down(mx, off));
    }
    __shared__ float smn[4], smx[4];
    int lane = tid & 63, wid = tid >> 6;
    if (lane == 0) { smn[wid] = mn; smx[wid] = mx; }
    __syncthreads();
    if (tid == 0) {
        mn = fminf(fminf(smn[0], smn[1]), fminf(smn[2], smn[3]));
        mx = fmaxf(fmaxf(smx[0], smx[1]), fmaxf(smx[2], smx[3]));
        atomicMin(&ws[img * 8 + b], enc_f(mn));
        atomicMax(&ws[16 + img * 8 + b], enc_f(mx));
    }
}

// Fused sliding-row SSIM.
//  - LDS stages float4 (a, b, (a+b)^2, (a-b)^2) per column: horizontal pass is
//    11x4 fma; vertical acc[11][4]; SSIM recovers sigma12/(sigma1+sigma2) from
//    the s/d channels (non-bit-exact but ~1e-6, threshold 1.8e-4).
//  - 2-deep register prefetch + non-draining row barrier: global loads issued
//    at iter i are consumed (committed to LDS) at iter i+1; no vmcnt(0) drain.
__global__ __launch_bounds__(256) void k_ssim(const float* __restrict__ img1,
                                              const float* __restrict__ img2,
                                              const int* __restrict__ mask_pos,
                                              const unsigned int* __restrict__ ws,
                                              double* __restrict__ acc_g) {
    __shared__ float rb[2][272 * 4];   // per buffer: 272 cols x float4
    __shared__ float red[4];

    const int tid = threadIdx.x;
    const int b  = blockIdx.z;
    const int cb = blockIdx.x * CPB;
    const int r0 = blockIdx.y * RPB;
    const int mp = mask_pos[b];

    // normalization params (identical math to the verified round-3 version)
    float mn1, sc1, mn2, sc2;
    {
        float mnA = dec_f(ws[b]),     mxA = dec_f(ws[16 + b]);
        float mnB = dec_f(ws[8 + b]), mxB = dec_f(ws[24 + b]);
        float rngA = mxA - mnA; float d0A = rngA + 1e-8f; double DA = (double)d0A; float MA = rngA / d0A;
        float rngB = mxB - mnB; float d0B = rngB + 1e-8f; double DB = (double)d0B; float MB = rngB / d0B;
        for (int j = 0; j < 7 - b; ++j) {
            float djA = MA + 1e-8f; DA *= (double)djA; MA = MA / djA;
            float djB = MB + 1e-8f; DB *= (double)djB; MB = MB / djB;
        }
        mn1 = mnA; sc1 = (float)(1.0 / DA);
        mn2 = mnB; sc2 = (float)(1.0 / DB);
    }
    float gw[11];
    {
        float s = 0.f;
#pragma unroll
        for (int k = 0; k < 11; ++k) {
            float x = (float)((k - 5) * (k - 5));
            gw[k] = expf(-x / 4.5f);
            s += gw[k];
        }
#pragma unroll
        for (int k = 0; k < 11; ++k) gw[k] = gw[k] / s;
    }

    // scalar bases pre-offset to row r0-5 (never dereferenced when row invalid)
    const float* bs1 = img1 + (size_t)b * (IMH * IMW) + (ptrdiff_t)(r0 - 5) * IMW + mp;
    const float* bs2 = img2 + (size_t)b * (IMH * IMW) + (ptrdiff_t)(r0 - 5) * IMW + mp;

    // column predicates / clamped offsets — invariant across rows
    const int mcA = cb + tid - 8;                      // buffer entry tid
    const bool okA = (unsigned)mcA < (unsigned)WM;
    const int mcB = cb + 248 + tid;                    // buffer entry 256+tid (tid<16)
    const bool okB = (unsigned)mcB < (unsigned)WM;
    unsigned voffA = (unsigned)(okA ? mcA : 0);
    unsigned voffB = (unsigned)(okB ? mcB : 0);

    // row loader: normalized (a,b) for entry tid in .x/.y, tail entry in .z/.w
    auto ldrow = [&](int rn, bool want, float4& out) {
        float va = 0.f, vb = 0.f, wa = 0.f, wb = 0.f;
        if (want && (unsigned)rn < (unsigned)IMH) {
            float x1 = bs1[voffA], x2 = bs2[voffA];
            va = okA ? (x1 - mn1) * sc1 : 0.f;
            vb = okA ? (x2 - mn2) * sc2 : 0.f;
            if (tid < 16) {                     // exec-masked: only 16 lanes fetch
                float y1 = bs1[voffB], y2 = bs2[voffB];
                wa = okB ? (y1 - mn1) * sc1 : 0.f;
                wb = okB ? (y2 - mn2) * sc2 : 0.f;
            }
        }
        voffA += IMW; voffB += IMW;
        out = make_float4(va, vb, wa, wb);
    };
    // commit held row to LDS as (a, b, (a+b)^2, (a-b)^2)
    auto commit = [&](float* buf, const float4& L) {
        float pa = L.x + L.y, ma = L.x - L.y;
        *(float4*)&buf[4 * tid] = make_float4(L.x, L.y, pa * pa, ma * ma);
        if (tid < 16) {
            float pb = L.z + L.w, mb = L.z - L.w;
            *(float4*)&buf[4 * (256 + tid)] = make_float4(L.z, L.w, pb * pb, mb * mb);
        }
    };

    float acc[11][4];
#pragma unroll
    for (int s = 0; s < 11; ++s)
#pragma unroll
        for (int ch = 0; ch < 4; ++ch) acc[s][ch] = 0.f;
    float local = 0.f;

    // prologue: rows r0-5 (commit now) and r0-4 (hold in regs)
    float4 held, fresh;
    ldrow(r0 - 5, true, fresh);
    ldrow(r0 - 4, true, held);
    commit(&rb[0][0], fresh);
    ROW_BARRIER();
    const float* cur = &rb[0][0];
    float* nxt = (float*)&rb[1][0];

    const unsigned rdoff = 4u * (unsigned)(tid + 3);   // first tap entry

#pragma unroll 1
    for (int g = 0; g < 4; ++g) {
#pragma unroll
        for (int p = 0; p < 11; ++p) {
            if (g == 3 && p > 8) continue;     // i>41: nothing left to complete
            const int i = g * 11 + p;          // consumes input row r0-5+i

            // 2-deep prefetch: row r0-3+i (consumed at iter i+2); rows beyond
            // r0+36 are never consumed -> don't load (i<=39 <=> g<3 || p<=6)
            float4 newL;
            ldrow(r0 - 3 + i, (p <= 6) || (g < 3), newL);

            // horizontal 11-tap, 4 channels, ds_read_b128 per tap
            float ha, hb2, hs, hd;
            {
                float4 e = *(const float4*)&cur[rdoff];
                float w = gw[0];
                ha = w * e.x; hb2 = w * e.y; hs = w * e.z; hd = w * e.w;
#pragma unroll
                for (int k = 1; k < 11; ++k) {
                    float4 ek = *(const float4*)&cur[rdoff + 4u * k];
                    float wk = gw[k];
                    ha  = fmaf(wk, ek.x, ha);
                    hb2 = fmaf(wk, ek.y, hb2);
                    hs  = fmaf(wk, ek.z, hs);
                    hd  = fmaf(wk, ek.w, hd);
                }
            }

            // vertical scatter; slot (p+10)%11 starts its window: overwrite-mul
#pragma unroll
            for (int s = 0; s < 11; ++s) {
                const float w = gw[(p + 10 - s) % 11];
                if (s == (p + 10) % 11) {
                    acc[s][0] = w * ha;  acc[s][1] = w * hb2;
                    acc[s][2] = w * hs;  acc[s][3] = w * hd;
                } else {
                    acc[s][0] = fmaf(w, ha,  acc[s][0]);
                    acc[s][1] = fmaf(w, hb2, acc[s][1]);
                    acc[s][2] = fmaf(w, hs,  acc[s][2]);
                    acc[s][3] = fmaf(w, hd,  acc[s][3]);
                }
            }

            // slot p completes output row r0 + i - 10  (i>=10 <=> g>=1 || p==10)
            if ((g >= 1) || (p == 10)) {
                float mu1 = acc[p][0], mu2 = acc[p][1];
                float sv  = acc[p][2], dv  = acc[p][3];
                float m11 = mu1 * mu1, m22 = mu2 * mu2, m12 = mu1 * mu2;
                float sig12x2 = 0.5f * (sv - dv) - 2.f * m12;       // 2*sigma12
                float sigsum  = 0.5f * (sv + dv) - m11 - m22;       // sigma1+sigma2
                float num = (2.f * m12 + 1e-4f) * (sig12x2 + 9e-4f);
                float den = (m11 + m22 + 1e-4f) * (sigsum + 9e-4f);
                local += __fdividef(num, den);
            }

            // commit row held in regs (loaded 2 iters ago; vmcnt wait lands here)
            commit(nxt, held);
            ROW_BARRIER();
            { const float* t = cur; cur = nxt; nxt = (float*)t; }
            held = newL;
        }
    }

    for (int off = 32; off; off >>= 1) local += __shfl_down(local, off);
    int lane = tid & 63, wid = tid >> 6;
    if (lane == 0) red[wid] = local;
    __syncthreads();
    if (tid == 0) {
        double s = (double)red[0] + (double)red[1] + (double)red[2] + (double)red[3];
        atomicAdd(acc_g, s);
    }
}

__global__ void k_final(const double* __restrict__ acc, float* __restrict__ out) {
    out[0] = (float)(acc[0] * (1.0 / 8388608.0));   // mean over 8*1*1024*1024
}

extern "C" void kernel_launch(void* const* d_in, const int* in_sizes, int n_in,
                              void* d_out, int out_size, void* d_ws, size_t ws_size,
                              hipStream_t stream) {
    const float* img1 = (const float*)d_in[0];
    const float* img2 = (const float*)d_in[1];
    const int* mask_pos = (const int*)d_in[2];
    unsigned int* ws = (unsigned int*)d_ws;
    double* acc = (double*)(ws + 80);
    float* out = (float*)d_out;

    hipLaunchKernelGGL(k_init, dim3(1), dim3(64), 0, stream, ws);
    hipLaunchKernelGGL(k_minmax, dim3(2048), dim3(256), 0, stream, img1, img2, mask_pos, ws);
    hipLaunchKernelGGL(k_ssim, dim3(WM / CPB, IMH / RPB, NB), dim3(256), 0, stream,
                       img1, img2, mask_pos, ws, acc);
    hipLaunchKernelGGL(k_final, dim3(1), dim3(1), 0, stream, acc, out);
}